// Round 1
// baseline (442.155 us; speedup 1.0000x reference)
//
#include <hip/hip_runtime.h>
#include <hip/hip_bf16.h>

typedef __attribute__((ext_vector_type(4))) float  f32x4;
typedef __attribute__((ext_vector_type(8))) short  bf16x8;
typedef unsigned short u16;

#define ALPHA 0.2f
#define NN 8192
#define FF 128

// ---------------- K1: h = x@W (fp32), write hT (bf16, transposed), s1, s2 ----
extern "C" __global__ void __launch_bounds__(256)
gat_pre(const float* __restrict__ x, const float* __restrict__ Wm,
        const float* __restrict__ av, u16* __restrict__ hT,
        float* __restrict__ s1v, float* __restrict__ s2v) {
  __shared__ float xs[16][256];   // 16 KB
  __shared__ float hs[16][128];   // 8 KB
  const int t  = threadIdx.x;
  const int i0 = blockIdx.x * 16;

  { // stage x tile, coalesced
    const int r = t >> 4, c0 = (t & 15) * 16;
    const f32x4* src = (const f32x4*)(x + (size_t)(i0 + r) * 256 + c0);
    f32x4* dst = (f32x4*)&xs[r][c0];
#pragma unroll
    for (int m = 0; m < 4; ++m) dst[m] = src[m];
  }
  __syncthreads();

  { // h: thread = col c (0..127) x row-half rh; 8 rows each
    const int c = t & 127, rh = t >> 7;
    float acc[8] = {0.f,0.f,0.f,0.f,0.f,0.f,0.f,0.f};
    for (int k = 0; k < 256; ++k) {
      const float wk = Wm[k * 128 + c];   // coalesced, L2-hot
#pragma unroll
      for (int r = 0; r < 8; ++r) acc[r] = fmaf(xs[rh * 8 + r][k], wk, acc[r]);
    }
#pragma unroll
    for (int r = 0; r < 8; ++r) hs[rh * 8 + r][c] = acc[r];
  }
  __syncthreads();

  { // write transposed bf16 copy: hT[c][i]
    const int c = t >> 1, rr = (t & 1) * 8;
    u16 u[8];
#pragma unroll
    for (int k = 0; k < 8; ++k) {
      __hip_bfloat16 b = __float2bfloat16(hs[rr + k][c]);
      u[k] = *reinterpret_cast<u16*>(&b);
    }
    *(uint4*)(hT + (size_t)c * NN + i0 + rr) = *(const uint4*)u;
  }

  { // s1/s2 per row: 16 threads per row, shfl reduce
    const int r = t >> 4, q = t & 15;
    float p1 = 0.f, p2 = 0.f;
#pragma unroll
    for (int m = 0; m < 8; ++m) {
      const int c = q * 8 + m;
      const float hv = hs[r][c];
      p1 = fmaf(hv, av[c], p1);
      p2 = fmaf(hv, av[128 + c], p2);
    }
    p1 += __shfl_xor(p1, 1); p1 += __shfl_xor(p1, 2);
    p1 += __shfl_xor(p1, 4); p1 += __shfl_xor(p1, 8);
    p2 += __shfl_xor(p2, 1); p2 += __shfl_xor(p2, 2);
    p2 += __shfl_xor(p2, 4); p2 += __shfl_xor(p2, 8);
    if (q == 0) { s1v[i0 + r] = p1; s2v[i0 + r] = p2; }
  }
}

// ---------------- K2: fused masked-softmax + PV via MFMA ---------------------
// 256 blocks x 512 thr (8 waves). Block: 32 rows. j-loop JB=128.
// wave w: row-strip rs=w&1 (16 rows), col-quarter cq=w>>1 (32 of 128 cols).
extern "C" __global__ void __launch_bounds__(512)
gat_main(const float* __restrict__ adj, const u16* __restrict__ hT,
         const float* __restrict__ s1v, const float* __restrict__ s2v,
         float* __restrict__ out) {
  __shared__ u16  wlds[32 * 128];    // 8 KB,  [i][j] bf16, XOR-swizzled
  __shared__ u16  hlds[128 * 128];   // 32 KB, [c][j] bf16, XOR-swizzled
  __shared__ float denl[32];

  const int t    = threadIdx.x;
  const int lane = t & 63;
  const int i0   = blockIdx.x * 32;
  const int li   = t >> 4;            // local row 0..31 (w-gen mapping)
  const int j8   = (t & 15) * 8;      // j offset within tile (w-gen)
  const int wid  = t >> 6;
  const int rs   = wid & 1;
  const int cq   = wid >> 1;
  const int hc   = t >> 2;            // h-stage: row of hT (= output col) 0..127
  const int hq   = t & 3;             // h-stage: 32-j chunk

  const float s1i = s1v[i0 + li];
  const float* adjrow = adj + (size_t)(i0 + li) * NN + j8;
  const u16*   hrow   = hT + (size_t)hc * NN + hq * 32;

  f32x4 acc0 = {0.f,0.f,0.f,0.f}, acc1 = {0.f,0.f,0.f,0.f};
  float den = 0.f;

  // reg-staged prefetch of tile js=0
  f32x4 a0 = *(const f32x4*)(adjrow);
  f32x4 a1 = *(const f32x4*)(adjrow + 4);
  f32x4 z0 = *(const f32x4*)(s2v + j8);
  f32x4 z1 = *(const f32x4*)(s2v + j8 + 4);
  uint4 hr0 = *(const uint4*)(hrow);
  uint4 hr1 = *(const uint4*)(hrow + 8);
  uint4 hr2 = *(const uint4*)(hrow + 16);
  uint4 hr3 = *(const uint4*)(hrow + 24);

  for (int js = 0; js < NN; js += 128) {
    __syncthreads();                      // LDS free (prev MFMA phase done)

    { // w = adj>0 ? exp(leakyrelu(s1+s2)) : 0 ; bf16 -> swizzled LDS
      bf16x8 wpack;
      float dstep = 0.f;
#pragma unroll
      for (int e = 0; e < 8; ++e) {
        const float adv = (e < 4) ? a0[e] : a1[e - 4];
        const float tz  = s1i + ((e < 4) ? z0[e] : z1[e - 4]);
        const float fz  = tz > 0.f ? tz : ALPHA * tz;
        const float w8  = adv > 0.f ? __expf(fz) : 0.f;
        dstep += w8;
        __hip_bfloat16 hb = __float2bfloat16(w8);
        wpack[e] = *reinterpret_cast<short*>(&hb);
      }
      den += dstep;
      *(bf16x8*)((char*)wlds + ((li * 256 + j8 * 2) ^ ((li & 7) << 4))) = wpack;

      char* hb = (char*)hlds;
      const int base = hc * 256 + hq * 64;
      const int sw   = (hc & 7) << 4;
      *(uint4*)(hb + ((base +  0) ^ sw)) = hr0;
      *(uint4*)(hb + ((base + 16) ^ sw)) = hr1;
      *(uint4*)(hb + ((base + 32) ^ sw)) = hr2;
      *(uint4*)(hb + ((base + 48) ^ sw)) = hr3;
    }
    __syncthreads();

    if (js + 128 < NN) {                  // prefetch next tile (overlaps MFMA)
      const float* ap = adjrow + js + 128;
      a0 = *(const f32x4*)(ap);
      a1 = *(const f32x4*)(ap + 4);
      const float* zp = s2v + js + 128 + j8;
      z0 = *(const f32x4*)(zp);
      z1 = *(const f32x4*)(zp + 4);
      const u16* hp2 = hrow + js + 128;
      hr0 = *(const uint4*)(hp2);
      hr1 = *(const uint4*)(hp2 + 8);
      hr2 = *(const uint4*)(hp2 + 16);
      hr3 = *(const uint4*)(hp2 + 24);
    }

#pragma unroll
    for (int ks = 0; ks < 4; ++ks) {      // 4 K-steps of 32
      const int arow = rs * 16 + (lane & 15);
      const int koff = (ks * 32 + ((lane >> 4) << 3)) * 2;
      const bf16x8 af = *(const bf16x8*)((char*)wlds +
                          ((arow * 256 + koff) ^ ((arow & 7) << 4)));
      const int bc0 = cq * 32 + (lane & 15);
      const bf16x8 b0 = *(const bf16x8*)((char*)hlds +
                          ((bc0 * 256 + koff) ^ ((bc0 & 7) << 4)));
      const int bc1 = bc0 + 16;
      const bf16x8 b1 = *(const bf16x8*)((char*)hlds +
                          ((bc1 * 256 + koff) ^ ((bc1 & 7) << 4)));
      acc0 = __builtin_amdgcn_mfma_f32_16x16x32_bf16(af, b0, acc0, 0, 0, 0);
      acc1 = __builtin_amdgcn_mfma_f32_16x16x32_bf16(af, b1, acc1, 0, 0, 0);
    }
  }

  // fp32 denominator: reduce 16 lanes sharing a row
  den += __shfl_xor(den, 1); den += __shfl_xor(den, 2);
  den += __shfl_xor(den, 4); den += __shfl_xor(den, 8);
  if ((t & 15) == 0) denl[li] = den;
  __syncthreads();

#pragma unroll
  for (int r = 0; r < 4; ++r) {           // C/D: row=(l>>4)*4+r, col=l&15 (m89)
    const int row  = rs * 16 + ((lane >> 4) << 2) + r;
    const float dv = denl[row];
    const int col0 = cq * 32 + (lane & 15);
    out[(size_t)(i0 + row) * FF + col0]      = acc0[r] / dv;
    out[(size_t)(i0 + row) * FF + col0 + 16] = acc1[r] / dv;
  }
}

extern "C" void kernel_launch(void* const* d_in, const int* in_sizes, int n_in,
                              void* d_out, int out_size, void* d_ws, size_t ws_size,
                              hipStream_t stream) {
  const float* x   = (const float*)d_in[0];
  const float* adj = (const float*)d_in[1];
  const float* Wm  = (const float*)d_in[2];
  const float* av  = (const float*)d_in[3];
  float* out = (float*)d_out;

  u16*   hT  = (u16*)d_ws;                              // 128*8192*2 = 2 MB
  float* s1v = (float*)((char*)d_ws + (size_t)FF * NN * 2);
  float* s2v = s1v + NN;

  gat_pre <<<NN / 16, 256, 0, stream>>>(x, Wm, av, hT, s1v, s2v);
  gat_main<<<NN / 32, 512, 0, stream>>>(adj, hT, s1v, s2v, out);
}